// Round 3
// baseline (254.480 us; speedup 1.0000x reference)
//
#include <hip/hip_runtime.h>
#include <stdint.h>

// ---------------------------------------------------------------------------
// MLP_42872363549033: ViT-B quantized MLP, exact-i8 formulation.
//   h   = gelu( quant(x,ka1) @ quant(W1,kw1)^T + b1 )
//   out = quant(h,ka2) @ quant(W2,kw2)^T + b2
// quant(x,K) = int8 * (K/127) exactly -> i8 MFMA with i32 accumulation.
//
// Round 2 (re-run; round-2 bench hit GPU acquisition timeout):
// 128x128 tile, BK=128 bytes, double-buffered LDS 2-phase pipeline
// (stage next tile || compute current), XOR-swizzled LDS (pre-swizzled global
// source + swizzled ds_read, 128B rows), s_setprio around MFMA cluster.
// ---------------------------------------------------------------------------

typedef __attribute__((ext_vector_type(4))) int i32x4;

static constexpr int MROWS = 12608;   // 64 * 197
static constexpr int MPAD  = 12672;   // 99 * 128
static constexpr int DDIM  = 768;
static constexpr int HDIM  = 3072;

// ---- quantize: f32 -> i8 (4 elems/thread, packed store) -------------------
__device__ __forceinline__ int quant_one(float x, float K) {
    float xc = x / K;
    xc = fminf(fmaxf(xc, -1.0f), 1.0f);
    return (int)rintf(xc * 127.0f);   // v_rndne round-half-even = jnp.round
}

__global__ void quant_kernel(const float* __restrict__ x, int8_t* __restrict__ q,
                             const float* __restrict__ kp, int nvalid4, int ntot4) {
    int i = blockIdx.x * 256 + threadIdx.x;
    if (i >= ntot4) return;
    int packed = 0;
    if (i < nvalid4) {
        float K = kp[0];
        float4 v = reinterpret_cast<const float4*>(x)[i];
        packed = (quant_one(v.x, K) & 255)
               | ((quant_one(v.y, K) & 255) << 8)
               | ((quant_one(v.z, K) & 255) << 16)
               | ((quant_one(v.w, K) & 255) << 24);
    }
    reinterpret_cast<int*>(q)[i] = packed;   // zero-fills padded rows
}

// ---- async global -> LDS, 16B per lane ------------------------------------
__device__ __forceinline__ void load16_to_lds(const int8_t* g, int8_t* l) {
    __builtin_amdgcn_global_load_lds(
        (const __attribute__((address_space(1))) void*)g,
        (__attribute__((address_space(3))) void*)l, 16, 0, 0);
}

// ---- i8 GEMM: 128x128 tile, BK=128, 4 waves (2x2), mfma_i32_16x16x64_i8 ---
// A: [MPAD][KD] K-major, B: [ND][KD] K-major. C[m,n] = sum_k A[m,k]*B[n,k].
// LDS tile layout: [128 rows][8 chunks of 16B], chunk slot = kc ^ (row&7).
template<int KD, int ND, bool EPI1>
__global__ __launch_bounds__(256, 2)
void gemm_i8_kernel(const int8_t* __restrict__ A, const int8_t* __restrict__ B,
                    int8_t* __restrict__ qout, float* __restrict__ fout,
                    const float* __restrict__ bias,
                    const float* __restrict__ kA, const float* __restrict__ kW,
                    const float* __restrict__ kQ) {
    __shared__ __align__(16) int8_t lds[2][2][128 * 128];   // [dbuf][A|B][16KB]

    const int tid  = threadIdx.x;
    const int lane = tid & 63;
    const int wave = tid >> 6;
    const int wr   = wave >> 1;      // wave row (0..1)
    const int wc   = wave & 1;       // wave col (0..1)
    const int bm   = blockIdx.y * 128;
    const int bn   = blockIdx.x * 128;

    i32x4 acc[4][4] = {};

    // ---- staging: 4 rounds/matrix; thread t covers row srow+32r, one 16B chunk.
    // LDS dest is linear (gld_lds requirement); SOURCE chunk pre-swizzled so
    // LDS slot s within a row holds global chunk s ^ (row&7).
    const int srow = tid >> 3;                               // 0..31
    const int soff = ((tid & 7) ^ (srow & 7)) << 4;          // swizzled chunk byte
    const int8_t* gA = A + (size_t)(bm + srow) * KD + soff;
    const int8_t* gB = B + (size_t)(bn + srow) * KD + soff;
    const int ldst = tid * 16;

#define STAGE(buf, ktb)                                                        \
    do {                                                                       \
        const int8_t* a_ = gA + (ktb);                                         \
        const int8_t* b_ = gB + (ktb);                                         \
        int8_t* la_ = &lds[buf][0][ldst];                                      \
        int8_t* lb_ = &lds[buf][1][ldst];                                      \
        load16_to_lds(a_,                    la_);                             \
        load16_to_lds(a_ + (size_t)32 * KD,  la_ + 4096);                      \
        load16_to_lds(a_ + (size_t)64 * KD,  la_ + 8192);                      \
        load16_to_lds(a_ + (size_t)96 * KD,  la_ + 12288);                     \
        load16_to_lds(b_,                    lb_);                             \
        load16_to_lds(b_ + (size_t)32 * KD,  lb_ + 4096);                      \
        load16_to_lds(b_ + (size_t)64 * KD,  lb_ + 8192);                      \
        load16_to_lds(b_ + (size_t)96 * KD,  lb_ + 12288);                     \
    } while (0)

    // ---- fragment read addressing (swizzled) ----
    // lane&15 = frag row, lane>>4 = 16B k-chunk (0..3); ks flips chunk bit 2.
    const int fr = lane & 15;
    const int q4 = lane >> 4;
    const int c0 = ((q4 ^ (fr & 7)) << 4);                   // ks=0 chunk byte
    int aoff[4], boff[4];
#pragma unroll
    for (int m = 0; m < 4; ++m) aoff[m] = (wr * 64 + m * 16 + fr) * 128 + c0;
#pragma unroll
    for (int n = 0; n < 4; ++n) boff[n] = (wc * 64 + n * 16 + fr) * 128 + c0;

    constexpr int NT = KD / 128;
    STAGE(0, 0);
    __syncthreads();               // drains vmcnt(0): tile 0 resident

    int cur = 0;
    for (int t = 0; t < NT; ++t) {
        if (t + 1 < NT) STAGE(cur ^ 1, (t + 1) * 128);   // prefetch next tile

        const int8_t* Ab = &lds[cur][0][0];
        const int8_t* Bb = &lds[cur][1][0];
#pragma unroll
        for (int ks = 0; ks < 2; ++ks) {
            const int kx = ks << 6;                       // XOR 64 = chunk bit 2
            i32x4 af[4], bf[4];
#pragma unroll
            for (int m = 0; m < 4; ++m)
                af[m] = *reinterpret_cast<const i32x4*>(Ab + (aoff[m] ^ kx));
#pragma unroll
            for (int n = 0; n < 4; ++n)
                bf[n] = *reinterpret_cast<const i32x4*>(Bb + (boff[n] ^ kx));
            __builtin_amdgcn_s_setprio(1);
#pragma unroll
            for (int m = 0; m < 4; ++m)
#pragma unroll
                for (int n = 0; n < 4; ++n)
                    acc[m][n] = __builtin_amdgcn_mfma_i32_16x16x64_i8(af[m], bf[n], acc[m][n], 0, 0, 0);
            __builtin_amdgcn_s_setprio(0);
        }
        __syncthreads();           // drains prefetch loads + protects LDS reads
        cur ^= 1;
    }
#undef STAGE

    // ---- epilogue ----
    const float sAW = kA[0] * kW[0] * (1.0f / 16129.0f);   // (kA/127)*(kW/127)
    float kq = 1.0f;
    if constexpr (EPI1) kq = kQ[0];

    const int row0 = bm + wr * 64 + (q4 << 2);
    const int col0 = bn + wc * 64 + fr;
#pragma unroll
    for (int m = 0; m < 4; ++m) {
#pragma unroll
        for (int n = 0; n < 4; ++n) {
            const int col = col0 + n * 16;
            const float bv = bias[col];
#pragma unroll
            for (int j = 0; j < 4; ++j) {
                const int row = row0 + m * 16 + j;
                float h = (float)acc[m][n][j] * sAW + bv;
                if constexpr (EPI1) {
                    float g  = 0.5f * h * (1.0f + erff(h * 0.70710678118654752f));
                    float xc = fminf(fmaxf(g / kq, -1.0f), 1.0f);
                    qout[(size_t)row * ND + col] = (int8_t)(int)rintf(xc * 127.0f);
                } else {
                    if (row < MROWS)
                        fout[(size_t)row * ND + col] = h;
                }
            }
        }
    }
}

// ---------------------------------------------------------------------------
extern "C" void kernel_launch(void* const* d_in, const int* in_sizes, int n_in,
                              void* d_out, int out_size, void* d_ws, size_t ws_size,
                              hipStream_t stream) {
    const float* hidden = (const float*)d_in[0];
    const float* W1     = (const float*)d_in[1];
    const float* b1     = (const float*)d_in[2];
    const float* W2     = (const float*)d_in[3];
    const float* b2     = (const float*)d_in[4];
    const float* ka1    = (const float*)d_in[5];
    const float* kw1    = (const float*)d_in[6];
    const float* ka2    = (const float*)d_in[7];
    const float* kw2    = (const float*)d_in[8];
    float* out = (float*)d_out;

    int8_t* a8  = (int8_t*)d_ws;                    //  [MPAD][DDIM]
    int8_t* w1q = a8  + (size_t)MPAD * DDIM;        //  [HDIM][DDIM]
    int8_t* w2q = w1q + (size_t)HDIM * DDIM;        //  [DDIM][HDIM]
    int8_t* h8  = w2q + (size_t)DDIM * HDIM;        //  [MPAD][HDIM]

    {
        int ntot4 = MPAD * DDIM / 4, nval4 = MROWS * DDIM / 4;
        quant_kernel<<<(ntot4 + 255) / 256, 256, 0, stream>>>(hidden, a8, ka1, nval4, ntot4);
    }
    {
        int n4 = HDIM * DDIM / 4;
        quant_kernel<<<(n4 + 255) / 256, 256, 0, stream>>>(W1, w1q, kw1, n4, n4);
        quant_kernel<<<(n4 + 255) / 256, 256, 0, stream>>>(W2, w2q, kw2, n4, n4);
    }

    gemm_i8_kernel<DDIM, HDIM, true>
        <<<dim3(HDIM / 128, MPAD / 128), 256, 0, stream>>>
        (a8, w1q, h8, nullptr, b1, ka1, kw1, ka2);

    gemm_i8_kernel<HDIM, DDIM, false>
        <<<dim3(DDIM / 128, MPAD / 128), 256, 0, stream>>>
        (h8, w2q, nullptr, out, b2, ka2, kw2, nullptr);
}

// Round 9
// 225.446 us; speedup vs baseline: 1.1288x; 1.1288x over previous
//
#include <hip/hip_runtime.h>
#include <stdint.h>

// ---------------------------------------------------------------------------
// MLP_42872363549033: ViT-B quantized MLP, exact-i8 formulation.
//   h   = gelu( quant(x,ka1) @ quant(W1,kw1)^T + b1 )
//   out = quant(h,ka2) @ quant(W2,kw2)^T + b2
// quant(x,K) = int8 * (K/127) exactly -> i8 MFMA with i32 accumulation.
//
// Round 4 kernel (6th submission; rounds 4-8 hit GPU acquisition timeout):
// static double-buffer (no runtime LDS indices), BK=64B (32KB LDS,
// ~4-5 blocks/CU), prefetch-before-compute, 2-way-free LDS swizzle
// (slot = chunk ^ ((row>>1)&3), pre-swizzled source + swizzled read),
// bijective XCD block swizzle, fused quant kernel, setprio around MFMA.
// ---------------------------------------------------------------------------

typedef __attribute__((ext_vector_type(4))) int i32x4;

static constexpr int MROWS = 12608;   // 64 * 197
static constexpr int MPAD  = 12672;   // 99 * 128
static constexpr int DDIM  = 768;
static constexpr int HDIM  = 3072;

__device__ __forceinline__ int quant_one(float x, float K) {
    float xc = x / K;
    xc = fminf(fmaxf(xc, -1.0f), 1.0f);
    return (int)rintf(xc * 127.0f);   // v_rndne round-half-even = jnp.round
}

// ---- fused quantize: hidden | W1 | W2 in one launch -----------------------
__global__ void quant_fused_kernel(const float* __restrict__ x,
                                   const float* __restrict__ w1,
                                   const float* __restrict__ w2,
                                   int8_t* __restrict__ a8,
                                   int8_t* __restrict__ w1q,
                                   int8_t* __restrict__ w2q,
                                   const float* __restrict__ ka1,
                                   const float* __restrict__ kw1,
                                   const float* __restrict__ kw2) {
    constexpr int G1 = MPAD * DDIM / 4;     // a8 groups (incl. pad rows)
    constexpr int GV = MROWS * DDIM / 4;    // valid a8 groups
    constexpr int G2 = HDIM * DDIM / 4;     // w1q / w2q groups
    int i = blockIdx.x * 256 + threadIdx.x;
    const float4* src; int* dst; float K; int idx; bool valid = true;
    if (i < G1) {
        idx = i;           src = (const float4*)x;  dst = (int*)a8;  K = ka1[0];
        valid = i < GV;                      // pad rows -> 0
    } else if (i < G1 + G2) {
        idx = i - G1;      src = (const float4*)w1; dst = (int*)w1q; K = kw1[0];
    } else if (i < G1 + 2 * G2) {
        idx = i - G1 - G2; src = (const float4*)w2; dst = (int*)w2q; K = kw2[0];
    } else return;
    int packed = 0;
    if (valid) {
        float4 v = src[idx];
        packed = (quant_one(v.x, K) & 255)
               | ((quant_one(v.y, K) & 255) << 8)
               | ((quant_one(v.z, K) & 255) << 16)
               | ((quant_one(v.w, K) & 255) << 24);
    }
    dst[idx] = packed;
}

// ---- async global -> LDS, 16B per lane ------------------------------------
__device__ __forceinline__ void load16_to_lds(const int8_t* g, const int8_t* l) {
    __builtin_amdgcn_global_load_lds(
        (const __attribute__((address_space(1))) void*)g,
        (__attribute__((address_space(3))) void*)l, 16, 0, 0);
}

// ---- i8 GEMM: 128x128 tile, BK=64B, 4 waves (2x2), mfma_i32_16x16x64_i8 ---
// A: [MPAD][KD] K-major, B: [ND][KD] K-major. C[m,n] = sum_k A[m,k]*B[n,k].
// LDS tile [128 rows][4 slots of 16B]; slot s holds global chunk s^((row>>1)&3).
template<int KD, int ND, bool EPI1>
__global__ __launch_bounds__(256, 3)
void gemm_i8_kernel(const int8_t* __restrict__ A, const int8_t* __restrict__ B,
                    int8_t* __restrict__ qout, float* __restrict__ fout,
                    const float* __restrict__ bias,
                    const float* __restrict__ kA, const float* __restrict__ kW,
                    const float* __restrict__ kQ) {
    __shared__ __align__(16) int8_t As0[128 * 64];
    __shared__ __align__(16) int8_t Bs0[128 * 64];
    __shared__ __align__(16) int8_t As1[128 * 64];
    __shared__ __align__(16) int8_t Bs1[128 * 64];

    const int tid  = threadIdx.x;
    const int lane = tid & 63;
    const int wave = tid >> 6;
    const int wr   = wave >> 1;
    const int wc   = wave & 1;

    // ---- bijective XCD-chunked block swizzle (m204 form) ----
    constexpr int NXB = ND / 128;
    const int nwg = gridDim.x;
    const int q   = nwg >> 3, r = nwg & 7;
    const int xcd = blockIdx.x & 7, loc = blockIdx.x >> 3;
    const int nb  = (xcd < r ? xcd * (q + 1) : r * (q + 1) + (xcd - r) * q) + loc;
    const int bm  = (nb / NXB) * 128;
    const int bn  = (nb % NXB) * 128;

    i32x4 acc[4][4] = {};

    // ---- staging: thread t -> row t>>2 (and +64), LDS slot t&3 (linear dest),
    //      global chunk (t&3) ^ ((row>>1)&3)  [row>>1 == t>>3]
    const int srow = tid >> 2;                                // 0..63
    const int soff = (((tid & 3) ^ ((tid >> 3) & 3)) << 4);
    const int8_t* gA = A + (size_t)(bm + srow) * KD + soff;
    const int8_t* gB = B + (size_t)(bn + srow) * KD + soff;
    const int ldst = tid * 16;

#define STAGE(LA, LB, ktb)                                                     \
    do {                                                                       \
        const int8_t* a_ = gA + (ktb);                                         \
        const int8_t* b_ = gB + (ktb);                                         \
        load16_to_lds(a_,                   LA + ldst);                        \
        load16_to_lds(a_ + (size_t)64 * KD, LA + 4096 + ldst);                 \
        load16_to_lds(b_,                   LB + ldst);                        \
        load16_to_lds(b_ + (size_t)64 * KD, LB + 4096 + ldst);                 \
    } while (0)

    // ---- fragment read addressing (swizzled, 2-way residual = free) ----
    const int fr = lane & 15;
    const int q4 = lane >> 4;
    const int cs = ((q4 ^ ((fr >> 1) & 3)) << 4);
    int aoff[4], boff[4];
#pragma unroll
    for (int m = 0; m < 4; ++m) aoff[m] = (wr * 64 + m * 16 + fr) * 64 + cs;
#pragma unroll
    for (int n = 0; n < 4; ++n) boff[n] = (wc * 64 + n * 16 + fr) * 64 + cs;

#define COMPUTE(LA, LB)                                                        \
    do {                                                                       \
        i32x4 af[4], bf[4];                                                    \
        _Pragma("unroll")                                                      \
        for (int m = 0; m < 4; ++m)                                            \
            af[m] = *reinterpret_cast<const i32x4*>(LA + aoff[m]);             \
        _Pragma("unroll")                                                      \
        for (int n = 0; n < 4; ++n)                                            \
            bf[n] = *reinterpret_cast<const i32x4*>(LB + boff[n]);             \
        __builtin_amdgcn_s_setprio(1);                                         \
        _Pragma("unroll")                                                      \
        for (int m = 0; m < 4; ++m)                                            \
            _Pragma("unroll")                                                  \
            for (int n = 0; n < 4; ++n)                                        \
                acc[m][n] = __builtin_amdgcn_mfma_i32_16x16x64_i8(             \
                    af[m], bf[n], acc[m][n], 0, 0, 0);                         \
        __builtin_amdgcn_s_setprio(0);                                         \
    } while (0)

    constexpr int NT = KD / 64;     // 12 (GEMM1) or 48 (GEMM2) — both even
    STAGE(As0, Bs0, 0);
    __syncthreads();                          // tile 0 resident

    for (int t = 0; t < NT; t += 2) {
        STAGE(As1, Bs1, (t + 1) * 64);        // prefetch odd tile
        COMPUTE(As0, Bs0);
        __syncthreads();                      // odd tile in; buf0 reads done
        if (t + 2 < NT) STAGE(As0, Bs0, (t + 2) * 64);
        COMPUTE(As1, Bs1);
        __syncthreads();
    }
#undef STAGE
#undef COMPUTE

    // ---- epilogue ----
    const float sAW = kA[0] * kW[0] * (1.0f / 16129.0f);   // (kA/127)*(kW/127)
    float kq = 1.0f;
    if constexpr (EPI1) kq = kQ[0];

    const int row0 = bm + wr * 64 + (q4 << 2);
    const int col0 = bn + wc * 64 + fr;
#pragma unroll
    for (int m = 0; m < 4; ++m) {
#pragma unroll
        for (int n = 0; n < 4; ++n) {
            const int col = col0 + n * 16;
            const float bv = bias[col];
#pragma unroll
            for (int j = 0; j < 4; ++j) {
                const int row = row0 + m * 16 + j;
                float h = (float)acc[m][n][j] * sAW + bv;
                if constexpr (EPI1) {
                    float g  = 0.5f * h * (1.0f + erff(h * 0.70710678118654752f));
                    float xc = fminf(fmaxf(g / kq, -1.0f), 1.0f);
                    qout[(size_t)row * ND + col] = (int8_t)(int)rintf(xc * 127.0f);
                } else {
                    if (row < MROWS)
                        fout[(size_t)row * ND + col] = h;
                }
            }
        }
    }
}

// ---------------------------------------------------------------------------
extern "C" void kernel_launch(void* const* d_in, const int* in_sizes, int n_in,
                              void* d_out, int out_size, void* d_ws, size_t ws_size,
                              hipStream_t stream) {
    const float* hidden = (const float*)d_in[0];
    const float* W1     = (const float*)d_in[1];
    const float* b1     = (const float*)d_in[2];
    const float* W2     = (const float*)d_in[3];
    const float* b2     = (const float*)d_in[4];
    const float* ka1    = (const float*)d_in[5];
    const float* kw1    = (const float*)d_in[6];
    const float* ka2    = (const float*)d_in[7];
    const float* kw2    = (const float*)d_in[8];
    float* out = (float*)d_out;

    int8_t* a8  = (int8_t*)d_ws;                    //  [MPAD][DDIM]
    int8_t* w1q = a8  + (size_t)MPAD * DDIM;        //  [HDIM][DDIM]
    int8_t* w2q = w1q + (size_t)HDIM * DDIM;        //  [DDIM][HDIM]
    int8_t* h8  = w2q + (size_t)DDIM * HDIM;        //  [MPAD][HDIM]

    {
        constexpr int GTOT = (MPAD * DDIM + 2 * HDIM * DDIM) / 4;
        quant_fused_kernel<<<(GTOT + 255) / 256, 256, 0, stream>>>(
            hidden, W1, W2, a8, w1q, w2q, ka1, kw1, kw2);
    }

    gemm_i8_kernel<DDIM, HDIM, true>
        <<<(HDIM / 128) * (MPAD / 128), 256, 0, stream>>>
        (a8, w1q, h8, nullptr, b1, ka1, kw1, ka2);

    gemm_i8_kernel<HDIM, DDIM, false>
        <<<(DDIM / 128) * (MPAD / 128), 256, 0, stream>>>
        (h8, w2q, nullptr, out, b2, ka2, kw2, nullptr);
}